// Round 4
// baseline (1119.275 us; speedup 1.0000x reference)
//
#include <hip/hip_runtime.h>
#include <stdint.h>
#include <math.h>

#define NB 4
#define NU 1024
#define NS 256
#define NF 16
#define ND 256
#define NEGV -1000000000.0f
#define NBLK (NB * NS)   // 1024 blocks in cooperative kernel
#define VBIT (1 << 14)
#define AGENT __HIP_MEMORY_SCOPE_AGENT

// ctrl layout (unsigned words, 64B-padded counters):
//   [16*b]          rel[b]       release word, batch b
//   [64 + 16*b]     cnt2[b]      master arrive counter, batch b
//   [128 + 16*b]    flag[b]      early-exit epoch (any valid proposal), batch b
//   [192], [193]    det[2]       connect dtype detection
//   [256 + (b*8+g)*16]  cntb[b][g]  bucket arrive counters (8 buckets x 32 blocks)

// ---------- detect connect dtype (int32 / float32 / byte), parallel ----------
__global__ __launch_bounds__(256) void k_detect(const uint8_t* __restrict__ conn,
                                                unsigned* __restrict__ det) {
  int i = blockIdx.x * 256 + threadIdx.x;   // 64 blocks -> 16384 threads x 4B = 64KB sample
  uchar4 v = ((const uchar4*)conn)[i];
  bool c0 = v.x != 0;
  bool c123 = (v.y | v.z | v.w) != 0;
  unsigned long long m0 = __ballot(c0);
  unsigned long long m1 = __ballot(c123);
  if ((threadIdx.x & 63) == 0) {
    if (m0) atomicOr(&det[0], 1u);
    if (m1) atomicOr(&det[1], 1u);
  }
}

// ---------- transpose connect -> bitmask [b][s][u/32] ----------
__global__ __launch_bounds__(256) void k_transpose(const uint8_t* __restrict__ conn,
                                                   const unsigned* __restrict__ det,
                                                   uint32_t* __restrict__ connT) {
  unsigned d0 = det[0], d1 = det[1];
  int f = (d1 == 0) ? 0 : ((d0 == 0) ? 1 : 2);
  int id = blockIdx.x * 256 + threadIdx.x;  // (b, w, s), s fastest -> coalesced reads
  int s = id & (NS - 1);
  int w = (id >> 8) & 31;
  int b = id >> 13;
  uint32_t word = 0;
  for (int j = 0; j < 32; ++j) {
    int u = w * 32 + j;
    int e = (b * NU + u) * NS + s;
    bool nz;
    if (f == 0)      nz = ((const int*)conn)[e] != 0;
    else if (f == 1) nz = ((const float*)conn)[e] != 0.0f;
    else             nz = conn[e] != 0;
    word |= (uint32_t)nz << j;
  }
  connT[(b * NS + s) * 32 + w] = word;
}

// ---------- WS_K[d][c] = sum_e W_k[d][e] * W_state[e][c] ----------
__global__ __launch_bounds__(256) void k_weights(const float* __restrict__ W_state,
                                                 const float* __restrict__ W_k,
                                                 float* __restrict__ WS_K) {
  int d = threadIdx.x;
  float a0 = 0, a1 = 0, a2 = 0, a3 = 0;
  for (int e = 0; e < ND; ++e) {
    float wk = W_k[d * ND + e];
    float4 w4 = ((const float4*)W_state)[e];
    a0 += wk * w4.x; a1 += wk * w4.y; a2 += wk * w4.z; a3 += wk * w4.w;
  }
  ((float4*)WS_K)[d] = make_float4(a0, a1, a2, a3);
}

// ---------- generic f32 GEMM: C[m,n] = alpha * sum_k (A[m,k]+bias[k]) * B[n,k] ----------
__global__ __launch_bounds__(256) void k_gemm(
    const float* __restrict__ A, const float* __restrict__ Bm, float* __restrict__ C,
    int K, int lda, int ldb, int ldc, long sA, long sB, long sC,
    const float* __restrict__ biasA, float alpha) {
  int z = blockIdx.z;
  A += (size_t)z * sA; Bm += (size_t)z * sB; C += (size_t)z * sC;
  int m0 = blockIdx.y * 64, n0 = blockIdx.x * 64;
  int t = threadIdx.x;
  int tx = t & 15, ty = t >> 4;
  __shared__ float As[16][68];
  __shared__ float Bs[16][68];
  float acc[4][4];
#pragma unroll
  for (int i = 0; i < 4; i++)
#pragma unroll
    for (int j = 0; j < 4; j++) acc[i][j] = 0.f;
  int lr = t >> 2;
  int kq = (t & 3) * 4;
  for (int k0 = 0; k0 < K; k0 += 16) {
    float4 av = *(const float4*)(A + (size_t)(m0 + lr) * lda + k0 + kq);
    if (biasA) {
      const float* bp = biasA + k0 + kq;
      av.x += bp[0]; av.y += bp[1]; av.z += bp[2]; av.w += bp[3];
    }
    As[kq + 0][lr] = av.x; As[kq + 1][lr] = av.y; As[kq + 2][lr] = av.z; As[kq + 3][lr] = av.w;
    float4 bv = *(const float4*)(Bm + (size_t)(n0 + lr) * ldb + k0 + kq);
    Bs[kq + 0][lr] = bv.x; Bs[kq + 1][lr] = bv.y; Bs[kq + 2][lr] = bv.z; Bs[kq + 3][lr] = bv.w;
    __syncthreads();
#pragma unroll
    for (int k = 0; k < 16; ++k) {
      float4 a = *(const float4*)&As[k][ty * 4];
      float4 bb = *(const float4*)&Bs[k][tx * 4];
      float am[4] = {a.x, a.y, a.z, a.w};
      float bn[4] = {bb.x, bb.y, bb.z, bb.w};
#pragma unroll
      for (int i = 0; i < 4; ++i)
#pragma unroll
        for (int j = 0; j < 4; ++j) acc[i][j] += am[i] * bn[j];
    }
    __syncthreads();
  }
#pragma unroll
  for (int i = 0; i < 4; ++i) {
    float4 o = make_float4(acc[i][0] * alpha, acc[i][1] * alpha,
                           acc[i][2] * alpha, acc[i][3] * alpha);
    *(float4*)(C + (size_t)(m0 + ty * 4 + i) * ldc + n0 + tx * 4) = o;
  }
}

// ---------- qc[bu][c] = inv_sqrt_d * sum_d q[bu][d] * WS_K[d][c], wave per row ----------
__global__ __launch_bounds__(256) void k_qc(const float* __restrict__ q,
                                            const float* __restrict__ WS_K,
                                            float* __restrict__ qc) {
  int row = blockIdx.x * 4 + (threadIdx.x >> 6);
  int ln = threadIdx.x & 63;
  const float* qr = q + (size_t)row * ND;
  float a0 = 0, a1 = 0, a2 = 0, a3 = 0;
  for (int d = ln; d < ND; d += 64) {
    float qv = qr[d];
    float4 w = ((const float4*)WS_K)[d];
    a0 += qv * w.x; a1 += qv * w.y; a2 += qv * w.z; a3 += qv * w.w;
  }
  for (int o = 32; o; o >>= 1) {
    a0 += __shfl_xor(a0, o); a1 += __shfl_xor(a1, o);
    a2 += __shfl_xor(a2, o); a3 += __shfl_xor(a3, o);
  }
  if (ln == 0)
    ((float4*)qc)[row] = make_float4(a0 * 0.0625f, a1 * 0.0625f, a2 * 0.0625f, a3 * 0.0625f);
}

// ---------- per-batch hierarchical barrier: RMW arrivals, LOAD polling ----------
// 256 blocks/batch = 8 buckets x 32. Counters cumulative across epochs.
__device__ __forceinline__ void bsync(unsigned* cntb, unsigned* cnt2, unsigned* rel,
                                      unsigned e) {
  __syncthreads();
  if (threadIdx.x == 0) {
    __threadfence();  // publish this block's proposal stores device-wide
    unsigned old = __hip_atomic_fetch_add(cntb, 1u, __ATOMIC_RELAXED, AGENT);
    if (old == 32u * e - 1u) {                 // last of my 32-block bucket
      unsigned o2 = __hip_atomic_fetch_add(cnt2, 1u, __ATOMIC_RELAXED, AGENT);
      if (o2 == 8u * e - 1u)                   // last bucket of the batch
        __hip_atomic_store(rel, e, __ATOMIC_RELEASE, AGENT);
    }
    while (__hip_atomic_load(rel, __ATOMIC_RELAXED, AGENT) < e)
      __builtin_amdgcn_s_sleep(2);
  }
  __syncthreads();
}

// ---------- the 32-step allocator: one block per (b,s), all state local ----------
__global__ __launch_bounds__(256, 4) void k_steps(
    const float* __restrict__ L0T, const float* __restrict__ qc,
    const float* __restrict__ users, const float* __restrict__ servers,
    const uint32_t* __restrict__ connT, const float* __restrict__ fd_onehot,
    const float* __restrict__ W_us, const float* __restrict__ fd_alpha,
    const float* __restrict__ fd_beta, const float* __restrict__ score_bias,
    volatile int* __restrict__ pinfoG, volatile float* __restrict__ plogG,
    volatile float* __restrict__ plsbG,
    unsigned* __restrict__ ctrl,
    uint32_t* __restrict__ allocW, float* __restrict__ capF, float* __restrict__ out) {
  __shared__ unsigned long long keyS[NU];
  __shared__ float lsumS[NU];
  __shared__ uint32_t fdS[NU];
  __shared__ float wred[8];
  __shared__ int wredi[4];
  __shared__ float bcv;
  __shared__ int bca;
  __shared__ int sAny;
  __shared__ float capS[4];

  const int bs = blockIdx.x;
  const int b = bs >> 8;
  const int sown = bs & 255;
  const int tid = threadIdx.x;
  const int wv = tid >> 6, ln = tid & 63;

  unsigned* rel = ctrl + 16 * b;
  unsigned* cnt2 = ctrl + 64 + 16 * b;
  unsigned* flag = ctrl + 128 + 16 * b;
  unsigned* cntb = ctrl + 256 + (b * 8 + (sown >> 5)) * 16;

  // scalar constants (recomputed per block; trivial)
  const float a_ = fd_alpha[0], be_ = fd_beta[0];
  const float t0 = tanhf(be_), t1 = tanhf(a_ + be_);
  const float sb = score_bias[0];
  const float w0 = W_us[0], w1 = W_us[1], w2 = W_us[2];

  int fid = 0;
  for (int f = 0; f < NF; ++f)
    if (fd_onehot[bs * NF + f] > 0.5f) { fid = f; break; }

  const float ic0 = servers[bs * 8 + 3], ic1 = servers[bs * 8 + 4];
  const float ic2 = servers[bs * 8 + 5], ic3 = servers[bs * 8 + 6];
  const float m0d = fmaxf(ic0, 1e-6f), m1d = fmaxf(ic1, 1e-6f);
  const float m2d = fmaxf(ic2, 1e-6f), m3d = fmaxf(ic3, 1e-6f);
  if (tid == 0) { capS[0] = ic0; capS[1] = ic1; capS[2] = ic2; capS[3] = ic3; }

  // hoisted per-user (thread owns users tid, tid+256, tid+512, tid+768 of batch b)
  float L0c[4], qc0[4], qc1[4], qc2[4], qc3[4], nax[4], nay[4], nbx[4], nby[4];
  uint32_t connw[4];
  uint32_t upk[4] = {0, 0, 0, 0};           // bits 0-15 fdmask, bits 16-17 rc
  float usv[4];                              // us_add part only (round-1 numerics)
  float logpv[4] = {0, 0, 0, 0};
  uint32_t abits = 0;                        // bit it: alloc[u_it, sown]
#pragma unroll
  for (int it = 0; it < 4; ++it) {
    int u = it * 256 + tid, gu = b * NU + u;
    L0c[it] = L0T[(size_t)bs * NU + u];
    float4 q4 = *(const float4*)(qc + gu * 4);
    qc0[it] = q4.x; qc1[it] = q4.y; qc2[it] = q4.z; qc3[it] = q4.w;
    float2 nA = *(const float2*)(users + gu * 8 + 2);
    float2 nB2 = *(const float2*)(users + gu * 8 + 4);
    nax[it] = nA.x; nay[it] = nA.y; nbx[it] = nB2.x; nby[it] = nB2.y;
    connw[it] = connT[bs * 32 + it * 8 + (tid >> 5)];
    usv[it] = w1;                            // rc=0: [0,1,0]@W_us
  }
  for (int i = tid; i < NU; i += 256) { keyS[i] = 0ull; lsumS[i] = 0.f; fdS[i] = 0u; }
  __syncthreads();

  for (int step = 0; step < 32; ++step) {
    // ---- phase A: this server's masked argmax / logsumexp over users ----
    float c0 = capS[0], c1 = capS[1], c2 = capS[2], c3 = capS[3];
    float cr0 = c0 / m0d, cr1 = c1 / m1d, cr2 = c2 / m2d, cr3 = c3 / m3d;
    float cand[4];
    float lmax = NEGV;
    int larg = 0x7fffffff;
#pragma unroll
    for (int it = 0; it < 4; ++it) {
      int u = it * 256 + tid;
      bool el = ((connw[it] >> (tid & 31)) & 1u) && !((abits >> it) & 1u) &&
                ((upk[it] & 0x30000u) != 0x30000u) &&
                c0 >= nax[it] && c1 >= nay[it] && c2 >= nbx[it] && c3 >= nby[it];
      float tt = ((upk[it] >> fid) & 1u) ? t0 : t1;
      float lg = L0c[it] + qc0[it] * cr0 + qc1[it] * cr1 + qc2[it] * cr2 + qc3[it] * cr3 +
                 sb + tt + usv[it];
      float cv = el ? lg : NEGV;
      cand[it] = cv;
      if (cv > lmax || (cv == lmax && u < larg)) { lmax = cv; larg = u; }
    }
    for (int o = 32; o; o >>= 1) {
      float ov = __shfl_xor(lmax, o);
      int oa = __shfl_xor(larg, o);
      if (ov > lmax || (ov == lmax && oa < larg)) { lmax = ov; larg = oa; }
    }
    if (ln == 0) { wred[wv] = lmax; wredi[wv] = larg; }
    __syncthreads();
    if (tid == 0) {
      float m = wred[0]; int a = wredi[0];
      for (int i = 1; i < 4; ++i)
        if (wred[i] > m || (wred[i] == m && wredi[i] < a)) { m = wred[i]; a = wredi[i]; }
      bcv = m; bca = a;
    }
    __syncthreads();
    float maxv = bcv;
    int argu = bca;
    float ls = expf(cand[0] - maxv) + expf(cand[1] - maxv) +
               expf(cand[2] - maxv) + expf(cand[3] - maxv);
    for (int o = 32; o; o >>= 1) ls += __shfl_xor(ls, o);
    if (ln == 0) wred[4 + wv] = ls;
    __syncthreads();
    if (tid == 0) {
      float s4 = wred[4] + wred[5] + wred[6] + wred[7];
      int validb = (maxv > -1e8f) ? VBIT : 0;
      int par = (step & 1) * NBLK;
      pinfoG[par + bs] = argu | (fid << 10) | validb;
      plogG[par + bs] = maxv;
      plsbG[par + bs] = -logf(s4);
      if (validb)
        __hip_atomic_fetch_max(flag, (unsigned)(step + 1), __ATOMIC_RELAXED, AGENT);
    }

    bsync(cntb, cnt2, rel, (unsigned)(step + 1));

    // ---- early exit: no valid proposal in this batch => state frozen forever ----
    if (tid == 0) sAny = (int)__hip_atomic_load(flag, __ATOMIC_RELAXED, AGENT);
    __syncthreads();
    if (sAny < step + 1) break;

    // ---- phase B: scatter proposals to per-user LDS slots, then consume ----
    {
      int pbase = (step & 1) * NBLK + b * NS;
      int pi = pinfoG[pbase + tid];          // thread tid <-> server tid of batch b
      if (pi & VBIT) {
        int pu = pi & 1023;
        unsigned vb = __float_as_uint(plogG[pbase + tid]);
        unsigned enc = (vb & 0x80000000u) ? ~vb : (vb | 0x80000000u);
        unsigned long long key = ((unsigned long long)enc << 32) | (unsigned)(255 - tid);
        atomicMax(&keyS[pu], key);
        atomicAdd(&lsumS[pu], plsbG[pbase + tid]);
        atomicOr(&fdS[pu], 1u << ((pi >> 10) & 15));
      }
      __syncthreads();
#pragma unroll
      for (int it = 0; it < 4; ++it) {
        unsigned long long key = keyS[it * 256 + tid];
        if (key) {
          int u = it * 256 + tid;
          float lsum = lsumS[u];
          uint32_t fda = fdS[u];
          keyS[u] = 0ull; lsumS[u] = 0.f; fdS[u] = 0u;
          int bests = 255 - (int)(key & 0xFFFFFFFFull);
          logpv[it] += lsum;
          uint32_t pk = upk[it];
          int r = (int)((pk >> 16) & 3) + 1;
          upk[it] = ((pk | fda) & 0xFFFFu) | ((uint32_t)r << 16);
          float rf = (float)r;
          usv[it] = w0 * (rf / 3.0f) + w1 * (fmaxf(3.0f - rf, 0.f) / 3.0f) +
                    ((r == 2) ? w2 : 0.f);
          if (bests == sown) {
            abits |= 1u << it;
            capS[0] = fmaxf(c0 - nax[it], 0.f);
            capS[1] = fmaxf(c1 - nay[it], 0.f);
            capS[2] = fmaxf(c2 - nbx[it], 0.f);
            capS[3] = fmaxf(c3 - nby[it], 0.f);
          }
        }
      }
      __syncthreads();
    }
  }

  // ---- outputs ----
#pragma unroll
  for (int it = 0; it < 4; ++it) {
    unsigned long long m = __ballot((abits >> it) & 1u);
    if (ln == 0)
      *(unsigned long long*)&allocW[bs * 32 + it * 8 + wv * 2] = m;
  }
  if (tid == 0)
    *(float4*)(capF + bs * 4) = make_float4(capS[0], capS[1], capS[2], capS[3]);
  if (sown == 0) {
    float a = logpv[0] + logpv[1] + logpv[2] + logpv[3];
    for (int o = 32; o; o >>= 1) a += __shfl_xor(a, o);
    if (ln == 0) wred[wv] = a;
    __syncthreads();
    if (tid == 0) out[b] = wred[0] + wred[1] + wred[2] + wred[3];
  }
}

// ================= fallback path (round-1, proven) =================
__global__ __launch_bounds__(256) void k_init(
    const float* __restrict__ servers, const float* __restrict__ fd_onehot,
    const float* __restrict__ W_us, const float* __restrict__ fd_alpha,
    const float* __restrict__ fd_beta, const float* __restrict__ score_bias,
    float* __restrict__ consts, int* __restrict__ rc, float* __restrict__ logp,
    uint32_t* __restrict__ fdmask, float* __restrict__ us_add,
    float* __restrict__ cap, int* __restrict__ fd_id, uint32_t* __restrict__ allocT) {
  int i = blockIdx.x * 256 + threadIdx.x;
  if (i == 0) {
    float a = fd_alpha[0], be = fd_beta[0];
    consts[0] = tanhf(be);
    consts[1] = tanhf(a + be);
    consts[2] = score_bias[0];
    consts[3] = W_us[0]; consts[4] = W_us[1]; consts[5] = W_us[2];
  }
  if (i < NB * NU) {
    rc[i] = 0; logp[i] = 0.f; fdmask[i] = 0u;
    us_add[i] = W_us[1];
  }
  if (i < NB * NS) {
    int fid = 0;
    for (int f = 0; f < NF; ++f) if (fd_onehot[i * NF + f] > 0.5f) { fid = f; break; }
    fd_id[i] = fid;
    for (int c = 0; c < 4; ++c) cap[i * 4 + c] = servers[i * 8 + 3 + c];
  }
  allocT[i] = 0u;
}

__global__ __launch_bounds__(256) void k_stepA(
    const float* __restrict__ L0T, const float* __restrict__ qc,
    const float* __restrict__ us_add, const int* __restrict__ rc,
    const uint32_t* __restrict__ connT, const uint32_t* __restrict__ allocT,
    const uint32_t* __restrict__ fdmask, const int* __restrict__ fd_id,
    const float* __restrict__ cap, const float* __restrict__ servers,
    const float* __restrict__ users, const float* __restrict__ consts,
    int* __restrict__ prop_u, float* __restrict__ prop_logit,
    float* __restrict__ logp_bs, int* __restrict__ valid) {
  int bs = blockIdx.x;
  int b = bs >> 8;
  int tid = threadIdx.x;
  float t0 = consts[0], t1 = consts[1], sb = consts[2];
  float4 c4 = *(const float4*)(cap + bs * 4);
  const float* srow = servers + bs * 8;
  float cr0 = c4.x / fmaxf(srow[3], 1e-6f);
  float cr1 = c4.y / fmaxf(srow[4], 1e-6f);
  float cr2 = c4.z / fmaxf(srow[5], 1e-6f);
  float cr3 = c4.w / fmaxf(srow[6], 1e-6f);
  int fid = fd_id[bs];
  const float* L0row = L0T + (size_t)bs * NU;
  int ubase = b * NU;
  float cand[4];
  float lmax = NEGV;
  int larg = tid;
#pragma unroll
  for (int it = 0; it < 4; ++it) {
    int u = (it << 8) + tid;
    int gu = ubase + u;
    uint32_t cw = connT[bs * 32 + (u >> 5)];
    uint32_t aw = allocT[bs * 32 + (u >> 5)];
    uint32_t bp = (uint32_t)(u & 31);
    bool el = ((cw >> bp) & 1u) && !((aw >> bp) & 1u) && (rc[gu] < 3);
    const float* up = users + gu * 8;
    float2 nA = *(const float2*)(up + 2);
    float2 nB = *(const float2*)(up + 4);
    el = el && (c4.x >= nA.x) && (c4.y >= nA.y) && (c4.z >= nB.x) && (c4.w >= nB.y);
    float4 q4 = *(const float4*)(qc + gu * 4);
    float tt = ((fdmask[gu] >> fid) & 1u) ? t0 : t1;
    float lg = L0row[u] + q4.x * cr0 + q4.y * cr1 + q4.z * cr2 + q4.w * cr3
               + sb + tt + us_add[gu];
    float cv = el ? lg : NEGV;
    cand[it] = cv;
    if (cv > lmax) { lmax = cv; larg = u; }
  }
  __shared__ float smax[256];
  __shared__ int sarg[256];
  smax[tid] = lmax; sarg[tid] = larg;
  __syncthreads();
  for (int o2 = 128; o2 > 0; o2 >>= 1) {
    if (tid < o2) {
      float v2 = smax[tid + o2]; int a2 = sarg[tid + o2];
      if (v2 > smax[tid] || (v2 == smax[tid] && a2 < sarg[tid])) {
        smax[tid] = v2; sarg[tid] = a2;
      }
    }
    __syncthreads();
  }
  float maxv = smax[0];
  int argu = sarg[0];
  __syncthreads();
  float ls = 0.f;
#pragma unroll
  for (int it = 0; it < 4; ++it) ls += expf(cand[it] - maxv);
  smax[tid] = ls;
  __syncthreads();
  for (int o2 = 128; o2 > 0; o2 >>= 1) {
    if (tid < o2) smax[tid] += smax[tid + o2];
    __syncthreads();
  }
  if (tid == 0) {
    prop_u[bs] = argu;
    prop_logit[bs] = maxv;
    valid[bs] = (maxv > -1e8f) ? 1 : 0;
    logp_bs[bs] = -logf(smax[0]);
  }
}

__global__ __launch_bounds__(256) void k_stepB(
    const int* __restrict__ prop_u, const float* __restrict__ prop_logit,
    const float* __restrict__ logp_bs, const int* __restrict__ valid,
    const int* __restrict__ fd_id, const float* __restrict__ users,
    const float* __restrict__ consts,
    uint32_t* __restrict__ allocT, int* __restrict__ rc, float* __restrict__ cap,
    float* __restrict__ logp, uint32_t* __restrict__ fdmask, float* __restrict__ us_add) {
  int id = blockIdx.x * 256 + threadIdx.x;
  int b = id >> 10;
  int u = id & 1023;
  int tid = threadIdx.x;
  __shared__ int spu[256];
  __shared__ float spl[256];
  __shared__ float slb[256];
  __shared__ int sv[256];
  __shared__ int sfid[256];
  int si = b * NS + tid;
  spu[tid] = prop_u[si]; spl[tid] = prop_logit[si]; slb[tid] = logp_bs[si];
  sv[tid] = valid[si]; sfid[tid] = fd_id[si];
  __syncthreads();
  float bestv = NEGV;
  int bests = -1;
  float lsum = 0.f;
  uint32_t fdadd = 0;
  for (int s = 0; s < NS; ++s) {
    if (sv[s] && spu[s] == u) {
      lsum += slb[s];
      fdadd |= 1u << sfid[s];
      float v = spl[s];
      if (v > bestv) { bestv = v; bests = s; }
    }
  }
  logp[id] += lsum;
  if (fdadd) fdmask[id] |= fdadd;
  int r = rc[id];
  if (bests >= 0) {
    atomicOr(&allocT[(b * NS + bests) * 32 + (u >> 5)], 1u << (u & 31));
    r += 1;
    rc[id] = r;
    const float* up = users + id * 8;
    float2 nA = *(const float2*)(up + 2);
    float2 nB = *(const float2*)(up + 4);
    float* cp = cap + (b * NS + bests) * 4;
    cp[0] = fmaxf(cp[0] - nA.x, 0.f);
    cp[1] = fmaxf(cp[1] - nA.y, 0.f);
    cp[2] = fmaxf(cp[2] - nB.x, 0.f);
    cp[3] = fmaxf(cp[3] - nB.y, 0.f);
  }
  float rf = (float)r;
  float wus0 = consts[3], wus1 = consts[4], wus2 = consts[5];
  us_add[id] = wus0 * (rf / 3.0f) + wus1 * (fmaxf(3.0f - rf, 0.f) / 3.0f)
               + ((r == 2) ? wus2 : 0.f);
}

__global__ __launch_bounds__(256) void k_logpsum(const float* __restrict__ logp,
                                                 float* __restrict__ out) {
  int b = blockIdx.x;
  int tid = threadIdx.x;
  __shared__ float sred[256];
  float acc = 0.f;
  for (int it = 0; it < 4; ++it) acc += logp[b * NU + it * 256 + tid];
  sred[tid] = acc;
  __syncthreads();
  for (int o2 = 128; o2 > 0; o2 >>= 1) {
    if (tid < o2) sred[tid] += sred[tid + o2];
    __syncthreads();
  }
  if (tid == 0) out[b] = sred[0];
}

// ---------- expand bitmask + cap to output layout ----------
__global__ __launch_bounds__(256) void k_store(const uint32_t* __restrict__ allocW,
                                               const float* __restrict__ capF,
                                               float* __restrict__ out) {
  int blk = blockIdx.x;
  if (blk < 1024) {
    int i4 = (blk * 256 + threadIdx.x) * 4;
    int b = i4 >> 18;
    int u = (i4 >> 8) & 1023;
    int s = i4 & 255;
    int base = (b * NS + s) * 32 + (u >> 5);
    uint32_t bitm = 1u << (u & 31);
    float4 o;
    o.x = (allocW[base] & bitm) ? 1.f : 0.f;
    o.y = (allocW[base + 32] & bitm) ? 1.f : 0.f;
    o.z = (allocW[base + 64] & bitm) ? 1.f : 0.f;
    o.w = (allocW[base + 96] & bitm) ? 1.f : 0.f;
    *(float4*)(out + 4 + i4) = o;
  } else {
    int b = blk - 1024;
    int s = threadIdx.x;
    float4 c = *(const float4*)(capF + (b * NS + s) * 4);
    *(float4*)(out + 4 + NB * NU * NS + (b * NS + s) * 4) = c;
  }
}

extern "C" void kernel_launch(void* const* d_in, const int* in_sizes, int n_in,
                              void* d_out, int out_size, void* d_ws, size_t ws_size,
                              hipStream_t stream) {
  const float* user_enc = (const float*)d_in[0];
  const float* server_enc = (const float*)d_in[1];
  const float* users = (const float*)d_in[2];
  const float* servers = (const float*)d_in[3];
  const uint8_t* connect = (const uint8_t*)d_in[4];
  const float* fd_onehot = (const float*)d_in[5];
  const float* W_state = (const float*)d_in[6];
  const float* b_state = (const float*)d_in[7];
  const float* W_q = (const float*)d_in[8];
  const float* W_k = (const float*)d_in[9];
  const float* W_us = (const float*)d_in[10];
  const float* fd_alpha = (const float*)d_in[11];
  const float* fd_beta = (const float*)d_in[12];
  const float* score_bias = (const float*)d_in[13];

  char* ws = (char*)d_ws;
  size_t off = 0;
  auto take = [&](size_t bytes) -> void* {
    size_t cur = off;
    off = (off + bytes + 255) & ~(size_t)255;
    return (void*)(ws + cur);
  };
  unsigned* ctrl = (unsigned*)take(8192);
  unsigned* det = ctrl + 192;
  float* q = (float*)take((size_t)NB * NU * ND * 4);
  float* kb = (float*)take((size_t)NB * NS * ND * 4);
  float* L0T = (float*)take((size_t)NB * NS * NU * 4);
  float* qc = (float*)take((size_t)NB * NU * 4 * 4);
  float* WS_K = (float*)take((size_t)ND * 4 * 4);
  uint32_t* connT = (uint32_t*)take((size_t)NB * NS * 32 * 4);
  int* pinfoG = (int*)take((size_t)2 * NBLK * 4);
  float* plogG = (float*)take((size_t)2 * NBLK * 4);
  float* plsbG = (float*)take((size_t)2 * NBLK * 4);
  uint32_t* allocW = (uint32_t*)take((size_t)NB * NS * 32 * 4);
  float* capF = (float*)take((size_t)NB * NS * 4 * 4);
  // fallback-only state
  float* consts = (float*)take(256);
  uint32_t* fdmask = (uint32_t*)take((size_t)NB * NU * 4);
  int* fd_id = (int*)take((size_t)NB * NS * 4);
  int* rc = (int*)take((size_t)NB * NU * 4);
  float* us_add = (float*)take((size_t)NB * NU * 4);
  float* logp = (float*)take((size_t)NB * NU * 4);
  int* prop_u = (int*)take((size_t)NB * NS * 4);
  float* prop_logit = (float*)take((size_t)NB * NS * 4);
  float* logp_bs = (float*)take((size_t)NB * NS * 4);
  int* valid = (int*)take((size_t)NB * NS * 4);
  float* outp = (float*)d_out;

  hipMemsetAsync(ctrl, 0, 8192, stream);
  k_detect<<<64, 256, 0, stream>>>(connect, det);
  k_transpose<<<128, 256, 0, stream>>>(connect, det, connT);
  k_weights<<<1, 256, 0, stream>>>(W_state, W_k, WS_K);
  k_gemm<<<dim3(ND / 64, (NB * NU) / 64, 1), 256, 0, stream>>>(
      user_enc, W_q, q, ND, ND, ND, ND, 0, 0, 0, nullptr, 1.f);
  k_gemm<<<dim3(ND / 64, (NB * NS) / 64, 1), 256, 0, stream>>>(
      server_enc, W_k, kb, ND, ND, ND, ND, 0, 0, 0, b_state, 1.f);
  k_qc<<<NB * NU / 4, 256, 0, stream>>>(q, WS_K, qc);
  k_gemm<<<dim3(NU / 64, NS / 64, NB), 256, 0, stream>>>(
      kb, q, L0T, ND, ND, ND, NU,
      (long)NS * ND, (long)NU * ND, (long)NS * NU, nullptr, 0.0625f);

  // ---- decide cooperative vs fallback (host-side, capture-safe, deterministic) ----
  int dev = 0;
  hipGetDevice(&dev);
  int coopAttr = 0, nCU = 0, occ = 0;
  hipDeviceGetAttribute(&coopAttr, hipDeviceAttributeCooperativeLaunch, dev);
  hipDeviceGetAttribute(&nCU, hipDeviceAttributeMultiprocessorCount, dev);
  hipError_t oe = hipOccupancyMaxActiveBlocksPerMultiprocessor(&occ, (const void*)k_steps, 256, 0);
  bool useCoop = (coopAttr != 0) && (oe == hipSuccess) && ((long)occ * nCU >= NBLK);

  if (useCoop) {
    void* args[] = {(void*)&L0T, (void*)&qc, (void*)&users, (void*)&servers,
                    (void*)&connT, (void*)&fd_onehot, (void*)&W_us, (void*)&fd_alpha,
                    (void*)&fd_beta, (void*)&score_bias, (void*)&pinfoG, (void*)&plogG,
                    (void*)&plsbG, (void*)&ctrl,
                    (void*)&allocW, (void*)&capF, (void*)&outp};
    hipError_t le = hipLaunchCooperativeKernel((const void*)k_steps, dim3(NBLK), dim3(256),
                                               args, 0, stream);
    if (le != hipSuccess) useCoop = false;
  }
  if (!useCoop) {
    k_init<<<128, 256, 0, stream>>>(servers, fd_onehot, W_us, fd_alpha, fd_beta, score_bias,
                                    consts, rc, logp, fdmask, us_add, capF, fd_id, allocW);
    for (int step = 0; step < 32; ++step) {
      k_stepA<<<NB * NS, 256, 0, stream>>>(L0T, qc, us_add, rc, connT, allocW, fdmask, fd_id,
                                           capF, servers, users, consts,
                                           prop_u, prop_logit, logp_bs, valid);
      k_stepB<<<(NB * NU) / 256, 256, 0, stream>>>(prop_u, prop_logit, logp_bs, valid, fd_id,
                                                   users, consts,
                                                   allocW, rc, capF, logp, fdmask, us_add);
    }
    k_logpsum<<<NB, 256, 0, stream>>>(logp, (float*)d_out);
  }
  k_store<<<1028, 256, 0, stream>>>(allocW, capF, (float*)d_out);
}

// Round 5
// 1110.901 us; speedup vs baseline: 1.0075x; 1.0075x over previous
//
#include <hip/hip_runtime.h>
#include <stdint.h>
#include <math.h>

#define NB 4
#define NU 1024
#define NS 256
#define NF 16
#define ND 256
#define NEGV -1000000000.0f
#define NBLK (NB * NS)   // 1024 blocks in cooperative kernel
#define VBIT (1 << 14)
#define AGENT __HIP_MEMORY_SCOPE_AGENT

// ctrl layout (unsigned words):
//   [32*b]            rel[b]     release word, batch b (128B padded)
//   [256], [257]      det[2]     connect dtype detection
//   [1024 + bs*32]    arrive[bs] per-block arrival slot (128B padded)
// total words: 1024 + 1024*32 = 33792  (135168 bytes)

// ---------- detect connect dtype (int32 / float32 / byte), parallel ----------
__global__ __launch_bounds__(256) void k_detect(const uint8_t* __restrict__ conn,
                                                unsigned* __restrict__ det) {
  int i = blockIdx.x * 256 + threadIdx.x;   // 64 blocks -> 16384 threads x 4B = 64KB sample
  uchar4 v = ((const uchar4*)conn)[i];
  bool c0 = v.x != 0;
  bool c123 = (v.y | v.z | v.w) != 0;
  unsigned long long m0 = __ballot(c0);
  unsigned long long m1 = __ballot(c123);
  if ((threadIdx.x & 63) == 0) {
    if (m0) atomicOr(&det[0], 1u);
    if (m1) atomicOr(&det[1], 1u);
  }
}

// ---------- transpose connect -> bitmask [b][s][u/32], coalesced via LDS ----------
__global__ __launch_bounds__(256) void k_transpose(const uint8_t* __restrict__ conn,
                                                   const unsigned* __restrict__ det,
                                                   uint32_t* __restrict__ connT) {
  unsigned d0 = det[0], d1 = det[1];
  int f = (d1 == 0) ? 0 : ((d0 == 0) ? 1 : 2);
  int blk = blockIdx.x;          // b*32 + ug ; 128 blocks
  int b = blk >> 5, ug = blk & 31;
  int u0 = ug * 32;
  int t = threadIdx.x;
  __shared__ uint8_t sm[32][260];
#pragma unroll 4
  for (int r = 0; r < 32; ++r) {
    int e = (b * NU + u0 + r) * NS + t;
    bool nz;
    if (f == 0)      nz = ((const int*)conn)[e] != 0;
    else if (f == 1) nz = ((const float*)conn)[e] != 0.0f;
    else             nz = conn[e] != 0;
    sm[r][t] = nz ? 1 : 0;
  }
  __syncthreads();
  uint32_t word = 0;
#pragma unroll
  for (int j = 0; j < 32; ++j) word |= (uint32_t)sm[j][t] << j;
  connT[(b * NS + t) * 32 + ug] = word;
}

// ---------- WS_K[d][c] = sum_e W_k[d][e] * W_state[e][c] (e ascending order) ----------
__global__ __launch_bounds__(256) void k_weights(const float* __restrict__ W_state,
                                                 const float* __restrict__ W_k,
                                                 float* __restrict__ WS_K) {
  int d = threadIdx.x;
  const float4* wk4 = (const float4*)(W_k + d * ND);
  const float4* ws4 = (const float4*)W_state;
  float a0 = 0, a1 = 0, a2 = 0, a3 = 0;
  for (int e4 = 0; e4 < ND / 4; ++e4) {
    float4 k4 = wk4[e4];
    float4 w0 = ws4[e4 * 4 + 0];
    a0 += k4.x * w0.x; a1 += k4.x * w0.y; a2 += k4.x * w0.z; a3 += k4.x * w0.w;
    float4 w1 = ws4[e4 * 4 + 1];
    a0 += k4.y * w1.x; a1 += k4.y * w1.y; a2 += k4.y * w1.z; a3 += k4.y * w1.w;
    float4 w2 = ws4[e4 * 4 + 2];
    a0 += k4.z * w2.x; a1 += k4.z * w2.y; a2 += k4.z * w2.z; a3 += k4.z * w2.w;
    float4 w3 = ws4[e4 * 4 + 3];
    a0 += k4.w * w3.x; a1 += k4.w * w3.y; a2 += k4.w * w3.z; a3 += k4.w * w3.w;
  }
  ((float4*)WS_K)[d] = make_float4(a0, a1, a2, a3);
}

// ---------- generic f32 GEMM: C[m,n] = alpha * sum_k (A[m,k]+bias[k]) * B[n,k] ----------
__global__ __launch_bounds__(256) void k_gemm(
    const float* __restrict__ A, const float* __restrict__ Bm, float* __restrict__ C,
    int K, int lda, int ldb, int ldc, long sA, long sB, long sC,
    const float* __restrict__ biasA, float alpha) {
  int z = blockIdx.z;
  A += (size_t)z * sA; Bm += (size_t)z * sB; C += (size_t)z * sC;
  int m0 = blockIdx.y * 64, n0 = blockIdx.x * 64;
  int t = threadIdx.x;
  int tx = t & 15, ty = t >> 4;
  __shared__ float As[16][68];
  __shared__ float Bs[16][68];
  float acc[4][4];
#pragma unroll
  for (int i = 0; i < 4; i++)
#pragma unroll
    for (int j = 0; j < 4; j++) acc[i][j] = 0.f;
  int lr = t >> 2;
  int kq = (t & 3) * 4;
  for (int k0 = 0; k0 < K; k0 += 16) {
    float4 av = *(const float4*)(A + (size_t)(m0 + lr) * lda + k0 + kq);
    if (biasA) {
      const float* bp = biasA + k0 + kq;
      av.x += bp[0]; av.y += bp[1]; av.z += bp[2]; av.w += bp[3];
    }
    As[kq + 0][lr] = av.x; As[kq + 1][lr] = av.y; As[kq + 2][lr] = av.z; As[kq + 3][lr] = av.w;
    float4 bv = *(const float4*)(Bm + (size_t)(n0 + lr) * ldb + k0 + kq);
    Bs[kq + 0][lr] = bv.x; Bs[kq + 1][lr] = bv.y; Bs[kq + 2][lr] = bv.z; Bs[kq + 3][lr] = bv.w;
    __syncthreads();
#pragma unroll
    for (int k = 0; k < 16; ++k) {
      float4 a = *(const float4*)&As[k][ty * 4];
      float4 bb = *(const float4*)&Bs[k][tx * 4];
      float am[4] = {a.x, a.y, a.z, a.w};
      float bn[4] = {bb.x, bb.y, bb.z, bb.w};
#pragma unroll
      for (int i = 0; i < 4; ++i)
#pragma unroll
        for (int j = 0; j < 4; ++j) acc[i][j] += am[i] * bn[j];
    }
    __syncthreads();
  }
#pragma unroll
  for (int i = 0; i < 4; ++i) {
    float4 o = make_float4(acc[i][0] * alpha, acc[i][1] * alpha,
                           acc[i][2] * alpha, acc[i][3] * alpha);
    *(float4*)(C + (size_t)(m0 + ty * 4 + i) * ldc + n0 + tx * 4) = o;
  }
}

// ---------- qc[bu][c] = inv_sqrt_d * sum_d q[bu][d] * WS_K[d][c], wave per row ----------
__global__ __launch_bounds__(256) void k_qc(const float* __restrict__ q,
                                            const float* __restrict__ WS_K,
                                            float* __restrict__ qc) {
  int row = blockIdx.x * 4 + (threadIdx.x >> 6);
  int ln = threadIdx.x & 63;
  const float* qr = q + (size_t)row * ND;
  float a0 = 0, a1 = 0, a2 = 0, a3 = 0;
  for (int d = ln; d < ND; d += 64) {
    float qv = qr[d];
    float4 w = ((const float4*)WS_K)[d];
    a0 += qv * w.x; a1 += qv * w.y; a2 += qv * w.z; a3 += qv * w.w;
  }
  for (int o = 32; o; o >>= 1) {
    a0 += __shfl_xor(a0, o); a1 += __shfl_xor(a1, o);
    a2 += __shfl_xor(a2, o); a3 += __shfl_xor(a3, o);
  }
  if (ln == 0)
    ((float4*)qc)[row] = make_float4(a0 * 0.0625f, a1 * 0.0625f, a2 * 0.0625f, a3 * 0.0625f);
}

// ---------- per-batch barrier: padded store-slots + scanner block, no RMW ----------
__device__ __forceinline__ void bsync2(unsigned* arrive, unsigned* rel,
                                       int b, int sown, unsigned e) {
  __shared__ int nr;
  __syncthreads();
  if (sown == 0) {
    // scanner: thread t watches the arrive slot of block (b*NS + t)
    unsigned* slot = arrive + (unsigned)(b * NS + threadIdx.x) * 32u;
    bool ready = (threadIdx.x == 0);           // own block doesn't store a slot
    for (;;) {
      if (threadIdx.x == 0) nr = 0;
      __syncthreads();
      if (!ready && __hip_atomic_load(slot, __ATOMIC_RELAXED, AGENT) >= e) ready = true;
      unsigned long long mm = __ballot(!ready);
      if (mm && (threadIdx.x & 63) == 0) atomicOr(&nr, 1);
      __syncthreads();
      if (nr == 0) break;
      __builtin_amdgcn_s_sleep(1);
    }
    if (threadIdx.x == 0) {
      __threadfence();                          // own proposals visible before release
      __hip_atomic_store(rel, e, __ATOMIC_RELEASE, AGENT);
    }
  } else if (threadIdx.x == 0) {
    __threadfence();                            // publish proposals before arrival
    __hip_atomic_store(arrive + (unsigned)(b * NS + sown) * 32u, e,
                       __ATOMIC_RELEASE, AGENT);
    while (__hip_atomic_load(rel, __ATOMIC_RELAXED, AGENT) < e)
      __builtin_amdgcn_s_sleep(2);
  }
  __syncthreads();
}

// ---------- the 32-step allocator: one block per (b,s), all state local ----------
__global__ __launch_bounds__(256, 4) void k_steps(
    const float* __restrict__ L0T, const float* __restrict__ qc,
    const float* __restrict__ users, const float* __restrict__ servers,
    const uint32_t* __restrict__ connT, const float* __restrict__ fd_onehot,
    const float* __restrict__ W_us, const float* __restrict__ fd_alpha,
    const float* __restrict__ fd_beta, const float* __restrict__ score_bias,
    volatile int* __restrict__ pinfoG, volatile float* __restrict__ plogG,
    volatile float* __restrict__ plsbG,
    unsigned* __restrict__ ctrl,
    uint32_t* __restrict__ allocW, float* __restrict__ capF, float* __restrict__ out) {
  __shared__ unsigned long long keyS[NU];
  __shared__ float lsumS[NU];
  __shared__ uint32_t fdS[NU];
  __shared__ float wred[8];
  __shared__ int wredi[4];
  __shared__ float bcv;
  __shared__ int bca;
  __shared__ int sAny;
  __shared__ float capS[4];

  const int bs = blockIdx.x;
  const int b = bs >> 8;
  const int sown = bs & 255;
  const int tid = threadIdx.x;
  const int wv = tid >> 6, ln = tid & 63;

  unsigned* rel = ctrl + 32 * b;
  unsigned* arrive = ctrl + 1024;

  // scalar constants (recomputed per block; trivial)
  const float a_ = fd_alpha[0], be_ = fd_beta[0];
  const float t0 = tanhf(be_), t1 = tanhf(a_ + be_);
  const float sb = score_bias[0];
  const float w0 = W_us[0], w1 = W_us[1], w2 = W_us[2];

  int fid = 0;
  for (int f = 0; f < NF; ++f)
    if (fd_onehot[bs * NF + f] > 0.5f) { fid = f; break; }

  const float ic0 = servers[bs * 8 + 3], ic1 = servers[bs * 8 + 4];
  const float ic2 = servers[bs * 8 + 5], ic3 = servers[bs * 8 + 6];
  const float m0d = fmaxf(ic0, 1e-6f), m1d = fmaxf(ic1, 1e-6f);
  const float m2d = fmaxf(ic2, 1e-6f), m3d = fmaxf(ic3, 1e-6f);
  if (tid == 0) { capS[0] = ic0; capS[1] = ic1; capS[2] = ic2; capS[3] = ic3; }

  // hoisted per-user (thread owns users tid, tid+256, tid+512, tid+768 of batch b)
  float L0c[4], qc0[4], qc1[4], qc2[4], qc3[4], nax[4], nay[4], nbx[4], nby[4];
  uint32_t connw[4];
  uint32_t upk[4] = {0, 0, 0, 0};           // bits 0-15 fdmask, bits 16-17 rc
  float usv[4];                              // us_add part only (round-1 numerics)
  float logpv[4] = {0, 0, 0, 0};
  uint32_t abits = 0;                        // bit it: alloc[u_it, sown]
#pragma unroll
  for (int it = 0; it < 4; ++it) {
    int u = it * 256 + tid, gu = b * NU + u;
    L0c[it] = L0T[(size_t)bs * NU + u];
    float4 q4 = *(const float4*)(qc + gu * 4);
    qc0[it] = q4.x; qc1[it] = q4.y; qc2[it] = q4.z; qc3[it] = q4.w;
    float2 nA = *(const float2*)(users + gu * 8 + 2);
    float2 nB2 = *(const float2*)(users + gu * 8 + 4);
    nax[it] = nA.x; nay[it] = nA.y; nbx[it] = nB2.x; nby[it] = nB2.y;
    connw[it] = connT[bs * 32 + it * 8 + (tid >> 5)];
    usv[it] = w1;                            // rc=0: [0,1,0]@W_us
  }
  for (int i = tid; i < NU; i += 256) { keyS[i] = 0ull; lsumS[i] = 0.f; fdS[i] = 0u; }
  __syncthreads();

  for (int step = 0; step < 32; ++step) {
    // ---- phase A: this server's masked argmax / logsumexp over users ----
    float c0 = capS[0], c1 = capS[1], c2 = capS[2], c3 = capS[3];
    float cr0 = c0 / m0d, cr1 = c1 / m1d, cr2 = c2 / m2d, cr3 = c3 / m3d;
    float cand[4];
    float lmax = NEGV;
    int larg = 0x7fffffff;
#pragma unroll
    for (int it = 0; it < 4; ++it) {
      int u = it * 256 + tid;
      bool el = ((connw[it] >> (tid & 31)) & 1u) && !((abits >> it) & 1u) &&
                ((upk[it] & 0x30000u) != 0x30000u) &&
                c0 >= nax[it] && c1 >= nay[it] && c2 >= nbx[it] && c3 >= nby[it];
      float tt = ((upk[it] >> fid) & 1u) ? t0 : t1;
      float lg = L0c[it] + qc0[it] * cr0 + qc1[it] * cr1 + qc2[it] * cr2 + qc3[it] * cr3 +
                 sb + tt + usv[it];
      float cv = el ? lg : NEGV;
      cand[it] = cv;
      if (cv > lmax || (cv == lmax && u < larg)) { lmax = cv; larg = u; }
    }
    for (int o = 32; o; o >>= 1) {
      float ov = __shfl_xor(lmax, o);
      int oa = __shfl_xor(larg, o);
      if (ov > lmax || (ov == lmax && oa < larg)) { lmax = ov; larg = oa; }
    }
    if (ln == 0) { wred[wv] = lmax; wredi[wv] = larg; }
    __syncthreads();
    if (tid == 0) {
      float m = wred[0]; int a = wredi[0];
      for (int i = 1; i < 4; ++i)
        if (wred[i] > m || (wred[i] == m && wredi[i] < a)) { m = wred[i]; a = wredi[i]; }
      bcv = m; bca = a;
    }
    __syncthreads();
    float maxv = bcv;
    int argu = bca;
    float ls = expf(cand[0] - maxv) + expf(cand[1] - maxv) +
               expf(cand[2] - maxv) + expf(cand[3] - maxv);
    for (int o = 32; o; o >>= 1) ls += __shfl_xor(ls, o);
    if (ln == 0) wred[4 + wv] = ls;
    __syncthreads();
    if (tid == 0) {
      float s4 = wred[4] + wred[5] + wred[6] + wred[7];
      int validb = (maxv > -1e8f) ? VBIT : 0;
      int par = (step & 1) * NBLK;
      pinfoG[par + bs] = argu | (fid << 10) | validb;
      plogG[par + bs] = maxv;
      plsbG[par + bs] = -logf(s4);
    }

    bsync2(arrive, rel, b, sown, (unsigned)(step + 1));

    // ---- phase B: read proposals; batch-wide any via ballot; scatter; consume ----
    {
      int pbase = (step & 1) * NBLK + b * NS;
      int pi = pinfoG[pbase + tid];          // thread tid <-> server tid of batch b
      if (tid == 0) sAny = 0;
      __syncthreads();
      unsigned long long mm = __ballot((pi & VBIT) != 0);
      if (mm && (tid & 63) == 0) atomicOr(&sAny, 1);
      __syncthreads();
      if (sAny == 0) break;                  // uniform: batch state frozen forever
      if (pi & VBIT) {
        int pu = pi & 1023;
        unsigned vb = __float_as_uint(plogG[pbase + tid]);
        unsigned enc = (vb & 0x80000000u) ? ~vb : (vb | 0x80000000u);
        unsigned long long key = ((unsigned long long)enc << 32) | (unsigned)(255 - tid);
        atomicMax(&keyS[pu], key);
        atomicAdd(&lsumS[pu], plsbG[pbase + tid]);
        atomicOr(&fdS[pu], 1u << ((pi >> 10) & 15));
      }
      __syncthreads();
#pragma unroll
      for (int it = 0; it < 4; ++it) {
        unsigned long long key = keyS[it * 256 + tid];
        if (key) {
          int u = it * 256 + tid;
          float lsum = lsumS[u];
          uint32_t fda = fdS[u];
          keyS[u] = 0ull; lsumS[u] = 0.f; fdS[u] = 0u;
          int bests = 255 - (int)(key & 0xFFFFFFFFull);
          logpv[it] += lsum;
          uint32_t pk = upk[it];
          int r = (int)((pk >> 16) & 3) + 1;
          upk[it] = ((pk | fda) & 0xFFFFu) | ((uint32_t)r << 16);
          float rf = (float)r;
          usv[it] = w0 * (rf / 3.0f) + w1 * (fmaxf(3.0f - rf, 0.f) / 3.0f) +
                    ((r == 2) ? w2 : 0.f);
          if (bests == sown) {
            abits |= 1u << it;
            capS[0] = fmaxf(c0 - nax[it], 0.f);
            capS[1] = fmaxf(c1 - nay[it], 0.f);
            capS[2] = fmaxf(c2 - nbx[it], 0.f);
            capS[3] = fmaxf(c3 - nby[it], 0.f);
          }
        }
      }
      __syncthreads();
    }
  }

  // ---- outputs ----
#pragma unroll
  for (int it = 0; it < 4; ++it) {
    unsigned long long m = __ballot((abits >> it) & 1u);
    if (ln == 0)
      *(unsigned long long*)&allocW[bs * 32 + it * 8 + wv * 2] = m;
  }
  if (tid == 0)
    *(float4*)(capF + bs * 4) = make_float4(capS[0], capS[1], capS[2], capS[3]);
  if (sown == 0) {
    float a = logpv[0] + logpv[1] + logpv[2] + logpv[3];
    for (int o = 32; o; o >>= 1) a += __shfl_xor(a, o);
    if (ln == 0) wred[wv] = a;
    __syncthreads();
    if (tid == 0) out[b] = wred[0] + wred[1] + wred[2] + wred[3];
  }
}

// ================= fallback path (round-1, proven) =================
__global__ __launch_bounds__(256) void k_init(
    const float* __restrict__ servers, const float* __restrict__ fd_onehot,
    const float* __restrict__ W_us, const float* __restrict__ fd_alpha,
    const float* __restrict__ fd_beta, const float* __restrict__ score_bias,
    float* __restrict__ consts, int* __restrict__ rc, float* __restrict__ logp,
    uint32_t* __restrict__ fdmask, float* __restrict__ us_add,
    float* __restrict__ cap, int* __restrict__ fd_id, uint32_t* __restrict__ allocT) {
  int i = blockIdx.x * 256 + threadIdx.x;
  if (i == 0) {
    float a = fd_alpha[0], be = fd_beta[0];
    consts[0] = tanhf(be);
    consts[1] = tanhf(a + be);
    consts[2] = score_bias[0];
    consts[3] = W_us[0]; consts[4] = W_us[1]; consts[5] = W_us[2];
  }
  if (i < NB * NU) {
    rc[i] = 0; logp[i] = 0.f; fdmask[i] = 0u;
    us_add[i] = W_us[1];
  }
  if (i < NB * NS) {
    int fid = 0;
    for (int f = 0; f < NF; ++f) if (fd_onehot[i * NF + f] > 0.5f) { fid = f; break; }
    fd_id[i] = fid;
    for (int c = 0; c < 4; ++c) cap[i * 4 + c] = servers[i * 8 + 3 + c];
  }
  allocT[i] = 0u;
}

__global__ __launch_bounds__(256) void k_stepA(
    const float* __restrict__ L0T, const float* __restrict__ qc,
    const float* __restrict__ us_add, const int* __restrict__ rc,
    const uint32_t* __restrict__ connT, const uint32_t* __restrict__ allocT,
    const uint32_t* __restrict__ fdmask, const int* __restrict__ fd_id,
    const float* __restrict__ cap, const float* __restrict__ servers,
    const float* __restrict__ users, const float* __restrict__ consts,
    int* __restrict__ prop_u, float* __restrict__ prop_logit,
    float* __restrict__ logp_bs, int* __restrict__ valid) {
  int bs = blockIdx.x;
  int b = bs >> 8;
  int tid = threadIdx.x;
  float t0 = consts[0], t1 = consts[1], sb = consts[2];
  float4 c4 = *(const float4*)(cap + bs * 4);
  const float* srow = servers + bs * 8;
  float cr0 = c4.x / fmaxf(srow[3], 1e-6f);
  float cr1 = c4.y / fmaxf(srow[4], 1e-6f);
  float cr2 = c4.z / fmaxf(srow[5], 1e-6f);
  float cr3 = c4.w / fmaxf(srow[6], 1e-6f);
  int fid = fd_id[bs];
  const float* L0row = L0T + (size_t)bs * NU;
  int ubase = b * NU;
  float cand[4];
  float lmax = NEGV;
  int larg = tid;
#pragma unroll
  for (int it = 0; it < 4; ++it) {
    int u = (it << 8) + tid;
    int gu = ubase + u;
    uint32_t cw = connT[bs * 32 + (u >> 5)];
    uint32_t aw = allocT[bs * 32 + (u >> 5)];
    uint32_t bp = (uint32_t)(u & 31);
    bool el = ((cw >> bp) & 1u) && !((aw >> bp) & 1u) && (rc[gu] < 3);
    const float* up = users + gu * 8;
    float2 nA = *(const float2*)(up + 2);
    float2 nB = *(const float2*)(up + 4);
    el = el && (c4.x >= nA.x) && (c4.y >= nA.y) && (c4.z >= nB.x) && (c4.w >= nB.y);
    float4 q4 = *(const float4*)(qc + gu * 4);
    float tt = ((fdmask[gu] >> fid) & 1u) ? t0 : t1;
    float lg = L0row[u] + q4.x * cr0 + q4.y * cr1 + q4.z * cr2 + q4.w * cr3
               + sb + tt + us_add[gu];
    float cv = el ? lg : NEGV;
    cand[it] = cv;
    if (cv > lmax) { lmax = cv; larg = u; }
  }
  __shared__ float smax[256];
  __shared__ int sarg[256];
  smax[tid] = lmax; sarg[tid] = larg;
  __syncthreads();
  for (int o2 = 128; o2 > 0; o2 >>= 1) {
    if (tid < o2) {
      float v2 = smax[tid + o2]; int a2 = sarg[tid + o2];
      if (v2 > smax[tid] || (v2 == smax[tid] && a2 < sarg[tid])) {
        smax[tid] = v2; sarg[tid] = a2;
      }
    }
    __syncthreads();
  }
  float maxv = smax[0];
  int argu = sarg[0];
  __syncthreads();
  float ls = 0.f;
#pragma unroll
  for (int it = 0; it < 4; ++it) ls += expf(cand[it] - maxv);
  smax[tid] = ls;
  __syncthreads();
  for (int o2 = 128; o2 > 0; o2 >>= 1) {
    if (tid < o2) smax[tid] += smax[tid + o2];
    __syncthreads();
  }
  if (tid == 0) {
    prop_u[bs] = argu;
    prop_logit[bs] = maxv;
    valid[bs] = (maxv > -1e8f) ? 1 : 0;
    logp_bs[bs] = -logf(smax[0]);
  }
}

__global__ __launch_bounds__(256) void k_stepB(
    const int* __restrict__ prop_u, const float* __restrict__ prop_logit,
    const float* __restrict__ logp_bs, const int* __restrict__ valid,
    const int* __restrict__ fd_id, const float* __restrict__ users,
    const float* __restrict__ consts,
    uint32_t* __restrict__ allocT, int* __restrict__ rc, float* __restrict__ cap,
    float* __restrict__ logp, uint32_t* __restrict__ fdmask, float* __restrict__ us_add) {
  int id = blockIdx.x * 256 + threadIdx.x;
  int b = id >> 10;
  int u = id & 1023;
  int tid = threadIdx.x;
  __shared__ int spu[256];
  __shared__ float spl[256];
  __shared__ float slb[256];
  __shared__ int sv[256];
  __shared__ int sfid[256];
  int si = b * NS + tid;
  spu[tid] = prop_u[si]; spl[tid] = prop_logit[si]; slb[tid] = logp_bs[si];
  sv[tid] = valid[si]; sfid[tid] = fd_id[si];
  __syncthreads();
  float bestv = NEGV;
  int bests = -1;
  float lsum = 0.f;
  uint32_t fdadd = 0;
  for (int s = 0; s < NS; ++s) {
    if (sv[s] && spu[s] == u) {
      lsum += slb[s];
      fdadd |= 1u << sfid[s];
      float v = spl[s];
      if (v > bestv) { bestv = v; bests = s; }
    }
  }
  logp[id] += lsum;
  if (fdadd) fdmask[id] |= fdadd;
  int r = rc[id];
  if (bests >= 0) {
    atomicOr(&allocT[(b * NS + bests) * 32 + (u >> 5)], 1u << (u & 31));
    r += 1;
    rc[id] = r;
    const float* up = users + id * 8;
    float2 nA = *(const float2*)(up + 2);
    float2 nB = *(const float2*)(up + 4);
    float* cp = cap + (b * NS + bests) * 4;
    cp[0] = fmaxf(cp[0] - nA.x, 0.f);
    cp[1] = fmaxf(cp[1] - nA.y, 0.f);
    cp[2] = fmaxf(cp[2] - nB.x, 0.f);
    cp[3] = fmaxf(cp[3] - nB.y, 0.f);
  }
  float rf = (float)r;
  float wus0 = consts[3], wus1 = consts[4], wus2 = consts[5];
  us_add[id] = wus0 * (rf / 3.0f) + wus1 * (fmaxf(3.0f - rf, 0.f) / 3.0f)
               + ((r == 2) ? wus2 : 0.f);
}

__global__ __launch_bounds__(256) void k_logpsum(const float* __restrict__ logp,
                                                 float* __restrict__ out) {
  int b = blockIdx.x;
  int tid = threadIdx.x;
  __shared__ float sred[256];
  float acc = 0.f;
  for (int it = 0; it < 4; ++it) acc += logp[b * NU + it * 256 + tid];
  sred[tid] = acc;
  __syncthreads();
  for (int o2 = 128; o2 > 0; o2 >>= 1) {
    if (tid < o2) sred[tid] += sred[tid + o2];
    __syncthreads();
  }
  if (tid == 0) out[b] = sred[0];
}

// ---------- expand bitmask + cap to output layout ----------
__global__ __launch_bounds__(256) void k_store(const uint32_t* __restrict__ allocW,
                                               const float* __restrict__ capF,
                                               float* __restrict__ out) {
  int blk = blockIdx.x;
  if (blk < 1024) {
    int i4 = (blk * 256 + threadIdx.x) * 4;
    int b = i4 >> 18;
    int u = (i4 >> 8) & 1023;
    int s = i4 & 255;
    int base = (b * NS + s) * 32 + (u >> 5);
    uint32_t bitm = 1u << (u & 31);
    float4 o;
    o.x = (allocW[base] & bitm) ? 1.f : 0.f;
    o.y = (allocW[base + 32] & bitm) ? 1.f : 0.f;
    o.z = (allocW[base + 64] & bitm) ? 1.f : 0.f;
    o.w = (allocW[base + 96] & bitm) ? 1.f : 0.f;
    *(float4*)(out + 4 + i4) = o;
  } else {
    int b = blk - 1024;
    int s = threadIdx.x;
    float4 c = *(const float4*)(capF + (b * NS + s) * 4);
    *(float4*)(out + 4 + NB * NU * NS + (b * NS + s) * 4) = c;
  }
}

extern "C" void kernel_launch(void* const* d_in, const int* in_sizes, int n_in,
                              void* d_out, int out_size, void* d_ws, size_t ws_size,
                              hipStream_t stream) {
  const float* user_enc = (const float*)d_in[0];
  const float* server_enc = (const float*)d_in[1];
  const float* users = (const float*)d_in[2];
  const float* servers = (const float*)d_in[3];
  const uint8_t* connect = (const uint8_t*)d_in[4];
  const float* fd_onehot = (const float*)d_in[5];
  const float* W_state = (const float*)d_in[6];
  const float* b_state = (const float*)d_in[7];
  const float* W_q = (const float*)d_in[8];
  const float* W_k = (const float*)d_in[9];
  const float* W_us = (const float*)d_in[10];
  const float* fd_alpha = (const float*)d_in[11];
  const float* fd_beta = (const float*)d_in[12];
  const float* score_bias = (const float*)d_in[13];

  char* ws = (char*)d_ws;
  size_t off = 0;
  auto take = [&](size_t bytes) -> void* {
    size_t cur = off;
    off = (off + bytes + 255) & ~(size_t)255;
    return (void*)(ws + cur);
  };
  const size_t ctrlBytes = (size_t)(1024 + NBLK * 32) * 4;   // 135168
  unsigned* ctrl = (unsigned*)take(ctrlBytes);
  unsigned* det = ctrl + 256;
  float* q = (float*)take((size_t)NB * NU * ND * 4);
  float* kb = (float*)take((size_t)NB * NS * ND * 4);
  float* L0T = (float*)take((size_t)NB * NS * NU * 4);
  float* qc = (float*)take((size_t)NB * NU * 4 * 4);
  float* WS_K = (float*)take((size_t)ND * 4 * 4);
  uint32_t* connT = (uint32_t*)take((size_t)NB * NS * 32 * 4);
  int* pinfoG = (int*)take((size_t)2 * NBLK * 4);
  float* plogG = (float*)take((size_t)2 * NBLK * 4);
  float* plsbG = (float*)take((size_t)2 * NBLK * 4);
  uint32_t* allocW = (uint32_t*)take((size_t)NB * NS * 32 * 4);
  float* capF = (float*)take((size_t)NB * NS * 4 * 4);
  // fallback-only state
  float* consts = (float*)take(256);
  uint32_t* fdmask = (uint32_t*)take((size_t)NB * NU * 4);
  int* fd_id = (int*)take((size_t)NB * NS * 4);
  int* rc = (int*)take((size_t)NB * NU * 4);
  float* us_add = (float*)take((size_t)NB * NU * 4);
  float* logp = (float*)take((size_t)NB * NU * 4);
  int* prop_u = (int*)take((size_t)NB * NS * 4);
  float* prop_logit = (float*)take((size_t)NB * NS * 4);
  float* logp_bs = (float*)take((size_t)NB * NS * 4);
  int* valid = (int*)take((size_t)NB * NS * 4);
  float* outp = (float*)d_out;

  hipMemsetAsync(ctrl, 0, ctrlBytes, stream);
  k_detect<<<64, 256, 0, stream>>>(connect, det);
  k_transpose<<<128, 256, 0, stream>>>(connect, det, connT);
  k_weights<<<1, 256, 0, stream>>>(W_state, W_k, WS_K);
  k_gemm<<<dim3(ND / 64, (NB * NU) / 64, 1), 256, 0, stream>>>(
      user_enc, W_q, q, ND, ND, ND, ND, 0, 0, 0, nullptr, 1.f);
  k_gemm<<<dim3(ND / 64, (NB * NS) / 64, 1), 256, 0, stream>>>(
      server_enc, W_k, kb, ND, ND, ND, ND, 0, 0, 0, b_state, 1.f);
  k_qc<<<NB * NU / 4, 256, 0, stream>>>(q, WS_K, qc);
  k_gemm<<<dim3(NU / 64, NS / 64, NB), 256, 0, stream>>>(
      kb, q, L0T, ND, ND, ND, NU,
      (long)NS * ND, (long)NU * ND, (long)NS * NU, nullptr, 0.0625f);

  // ---- decide cooperative vs fallback (host-side, capture-safe, deterministic) ----
  int dev = 0;
  hipGetDevice(&dev);
  int coopAttr = 0, nCU = 0, occ = 0;
  hipDeviceGetAttribute(&coopAttr, hipDeviceAttributeCooperativeLaunch, dev);
  hipDeviceGetAttribute(&nCU, hipDeviceAttributeMultiprocessorCount, dev);
  hipError_t oe = hipOccupancyMaxActiveBlocksPerMultiprocessor(&occ, (const void*)k_steps, 256, 0);
  bool useCoop = (coopAttr != 0) && (oe == hipSuccess) && ((long)occ * nCU >= NBLK);

  if (useCoop) {
    void* args[] = {(void*)&L0T, (void*)&qc, (void*)&users, (void*)&servers,
                    (void*)&connT, (void*)&fd_onehot, (void*)&W_us, (void*)&fd_alpha,
                    (void*)&fd_beta, (void*)&score_bias, (void*)&pinfoG, (void*)&plogG,
                    (void*)&plsbG, (void*)&ctrl,
                    (void*)&allocW, (void*)&capF, (void*)&outp};
    hipError_t le = hipLaunchCooperativeKernel((const void*)k_steps, dim3(NBLK), dim3(256),
                                               args, 0, stream);
    if (le != hipSuccess) useCoop = false;
  }
  if (!useCoop) {
    k_init<<<128, 256, 0, stream>>>(servers, fd_onehot, W_us, fd_alpha, fd_beta, score_bias,
                                    consts, rc, logp, fdmask, us_add, capF, fd_id, allocW);
    for (int step = 0; step < 32; ++step) {
      k_stepA<<<NB * NS, 256, 0, stream>>>(L0T, qc, us_add, rc, connT, allocW, fdmask, fd_id,
                                           capF, servers, users, consts,
                                           prop_u, prop_logit, logp_bs, valid);
      k_stepB<<<(NB * NU) / 256, 256, 0, stream>>>(prop_u, prop_logit, logp_bs, valid, fd_id,
                                                   users, consts,
                                                   allocW, rc, capF, logp, fdmask, us_add);
    }
    k_logpsum<<<NB, 256, 0, stream>>>(logp, (float*)d_out);
  }
  k_store<<<1028, 256, 0, stream>>>(allocW, capF, (float*)d_out);
}